// Round 2
// 676.726 us; speedup vs baseline: 1.2743x; 1.2743x over previous
//
#include <hip/hip_runtime.h>
#include <hip/hip_bf16.h>

#define T_STEPS 2048
#define BATCH   256
#define DIM     128
#define INV2PI  0.15915494309189535f

#define ZX_FLOATS (T_STEPS * BATCH * 16)

// ---------------------------------------------------------------------------
// prep: pack weights Wc[d*16 + (g*4+k)] = W_g[d*4+k] * (1/2pi),
//       bt[u] = (b_g[k]+theta_g[k]) * (1/2pi).
// The 1/2pi fold removes one multiply from the recurrence critical path:
// z only ever feeds cos(2*pi*fract(.)), so scaling W,b,theta (but NOT h)
// by 1/2pi is exact up to fp rounding.
// ---------------------------------------------------------------------------
__global__ __launch_bounds__(64) void prep(
    const float* __restrict__ Wf, const float* __restrict__ bf, const float* __restrict__ tf,
    const float* __restrict__ Wi, const float* __restrict__ bi, const float* __restrict__ ti,
    const float* __restrict__ Wu, const float* __restrict__ bu, const float* __restrict__ tu,
    const float* __restrict__ Wo, const float* __restrict__ bo, const float* __restrict__ to_,
    float* __restrict__ Wc, float* __restrict__ bt)
{
    const int tid = threadIdx.x;
    for (int idx = tid; idx < DIM * 16; idx += 64) {
        int d = idx >> 4, u = idx & 15, g = u >> 2, k = u & 3;
        const float* W = (g == 0) ? Wf : (g == 1) ? Wi : (g == 2) ? Wu : Wo;
        Wc[idx] = W[d * 4 + k] * INV2PI;
    }
    if (tid < 16) {
        int g = tid >> 2, k = tid & 3;
        const float* bb = (g == 0) ? bf : (g == 1) ? bi : (g == 2) ? bo : bo;
        const float* tt = (g == 0) ? tf : (g == 1) ? ti : (g == 2) ? tu : to_;
        // NOTE: g==2 must be bu/tu — guard against typo by explicit table:
        const float* btab[4] = { bf, bi, bu, bo };
        const float* ttab[4] = { tf, ti, tu, to_ };
        bb = btab[g]; tt = ttab[g];
        bt[tid] = (bb[k] + tt[k]) * INV2PI;
    }
}

// ---------------------------------------------------------------------------
// Kernel 1 v5: the v4 inner loop mixed ds_read_b32 (x from LDS) with s_load
// (weights) every iteration; SMEM+DS share lgkmcnt and SMEM is out-of-order,
// so each consume forced lgkmcnt(0) full drains -> 128 serialized stalls per
// pass. v5: pad 33 -> 36 (conflict-free AND 16B-aligned), batch-copy each
// lane's 32-float chunk LDS -> registers with 8 ds_read_b128, then the FMA
// loop has NO DS ops in flight: pure SGPR weight stream + register x.
// LDS/block = 36864 B -> still 4 blocks/CU (147456 <= 163840).
// ---------------------------------------------------------------------------
__global__ __launch_bounds__(256) void zx_gemm(
    const float4* __restrict__ x4,
    const float*  __restrict__ Wc,    // [128][16] packed, prescaled
    const float*  __restrict__ btv,   // [16] prescaled
    float4*       __restrict__ Zx4)
{
    __shared__ float xs[4][64 * 36];          // 36864 B total
    const int lane = threadIdx.x & 63;
    const int wid  = threadIdx.x >> 6;
    float* myxs = xs[wid];
    const size_t wrow0 = ((size_t)blockIdx.x * 4 + wid) * 64;

    float acc[16];
#pragma unroll
    for (int u = 0; u < 16; ++u) acc[u] = btv[u];   // uniform -> s_load

    const int r0 = lane >> 3;                 // 0..7
    const int q  = lane & 7;                  // 0..7

#pragma unroll
    for (int c = 0; c < 4; ++c) {
        float4 v[8];
#pragma unroll
        for (int i = 0; i < 8; ++i)
            v[i] = x4[(wrow0 + i * 8 + r0) * 32 + c * 8 + q];
        // pad-36 keeps stores 16B-aligned (b128) and write banks perfectly
        // even: start bank 4*(r0+q) mod 32, 8 accesses per bank column.
#pragma unroll
        for (int i = 0; i < 8; ++i)
            *(float4*)&myxs[(i * 8 + r0) * 36 + q * 4] = v[i];

        // same-wave DS ops execute in order; compiler inserts lgkmcnt waits.
        // Batch LDS -> regs: 8 x ds_read_b128, banks 4*lane+4j mod 32 -> the
        // minimal 8 bank-cycles per op, no extra conflict.
        float xr[32];
#pragma unroll
        for (int j = 0; j < 8; ++j) {
            float4 tv = *(const float4*)&myxs[lane * 36 + j * 4];
            xr[j * 4 + 0] = tv.x; xr[j * 4 + 1] = tv.y;
            xr[j * 4 + 2] = tv.z; xr[j * 4 + 3] = tv.w;
        }
        // compute phase: only SMEM in flight -> pipelineable lgkm waits
#pragma unroll
        for (int dd = 0; dd < 32; ++dd) {
            const float xv = xr[dd];
            const float* w = &Wc[(c * 32 + dd) * 16]; // uniform -> s_load
#pragma unroll
            for (int u = 0; u < 16; ++u) acc[u] = fmaf(xv, w[u], acc[u]);
        }
    }

    size_t orow = wrow0 + lane;
    float4* zr = &Zx4[orow * 4];
    zr[0] = make_float4(acc[0],  acc[1],  acc[2],  acc[3]);
    zr[1] = make_float4(acc[4],  acc[5],  acc[6],  acc[7]);
    zr[2] = make_float4(acc[8],  acc[9],  acc[10], acc[11]);
    zr[3] = make_float4(acc[12], acc[13], acc[14], acc[15]);
}

// ---------------------------------------------------------------------------
// Kernel 2 v4: the v3 wave packed 2 chains (A/B); measured 559 cyc/step ~=
// 2 chains x ~50 inst x 2 cyc + trans/hazards => ISSUE-bound (VALUBusy math:
// ~70% issue occupancy on the one active SIMD). There are 256 batches x 16
// lanes = 64 full waves of work: go to 1 chain per 16-lane group, 64 blocks.
// Per-wave issue halves; step time drops toward the dependency chain.
// 1/2pi is pre-folded into Zx and wh (one fewer mul on the serial path).
// DPP select network kept bit-identical to the verified v3.
// ---------------------------------------------------------------------------
template<int CTRL>
__device__ __forceinline__ float fdpp(float x) {
    return __int_as_float(__builtin_amdgcn_update_dpp(
        0, __float_as_int(x), CTRL, 0xF, 0xF, true));
}

__device__ __forceinline__ float lstm_step(
    float& h, float& c, float zb,
    float wh0, float wh1, float wh2, float wh3,
    float s1c, float m2, float m3, int k, bool b0g, bool b1g)
{
    float h0 = fdpp<0x00>(h), h1 = fdpp<0x55>(h), h2 = fdpp<0xAA>(h), h3 = fdpp<0xFF>(h);
    float t1 = fmaf(h2, wh2, h3 * wh3);
    float z  = fmaf(h1, wh1, fmaf(h0, wh0, zb)) + t1;   // already in revolutions

    float cs = __builtin_amdgcn_cosf(__builtin_amdgcn_fractf(z));

    float q0 = fdpp<0x00>(cs), q1 = fdpp<0x55>(cs), q2 = fdpp<0xAA>(cs);
    float p = (q0 * (k >= 1 ? q1 : 1.f)) * ((k >= 2 ? q2 : 1.f) * (k == 3 ? cs : 1.f));

    float e = __builtin_amdgcn_exp2f(p * s1c);
    float y = fmaf(__builtin_amdgcn_rcpf(1.f + e), m2, m3);

    float mm  = fdpp<0x1B>(y);
    float y4  = fdpp<0x141>(mm);
    float y8  = fdpp<0x128>(y);
    float y12 = fdpp<0x128>(y4);
    float t01  = b0g ? y4  : y,  t01s = b0g ? y  : y4;
    float t23  = b0g ? y12 : y8, t23s = b0g ? y8 : y12;
    float fv = b1g ? t23  : t01;
    float iv = b1g ? t23s : t01s;
    float gv = b1g ? t01  : t23;
    float ov = b1g ? t01s : t23s;

    c = fmaf(fv, c, iv * gv);
    float e2 = __builtin_amdgcn_exp2f(c * -2.885390082f);
    float th = fmaf(2.f, __builtin_amdgcn_rcpf(1.f + e2), -1.f);
    h = ov * th;
    return h;
}

__global__ __launch_bounds__(64) void qlstm_rec(
    const float* __restrict__ Zx,
    const float* __restrict__ Wf, const float* __restrict__ Wi,
    const float* __restrict__ Wu, const float* __restrict__ Wo,
    float* __restrict__ out)
{
    const int tid = threadIdx.x;
    const int u   = tid & 15;
    const int g   = u >> 2;
    const int k   = u & 3;
    const int b   = blockIdx.x * 4 + (tid >> 4);   // 64 blocks x 4 batches

    const float* Wg = (g == 0) ? Wf : (g == 1) ? Wi : (g == 2) ? Wu : Wo;
    const float wh0 = Wg[(DIM + 0) * 4 + k] * INV2PI;
    const float wh1 = Wg[(DIM + 1) * 4 + k] * INV2PI;
    const float wh2 = Wg[(DIM + 2) * 4 + k] * INV2PI;
    const float wh3 = Wg[(DIM + 3) * 4 + k] * INV2PI;

    const bool  isg = (g == 2);
    const float s1c = isg ? -2.885390082f : -1.442695041f;
    const float m2  = isg ? 2.f : 1.f;
    const float m3  = isg ? -1.f : 0.f;
    const bool  b0g = (g & 1) != 0;
    const bool  b1g = (g & 2) != 0;

    const float* zp = Zx + b * 16 + u;      // step stride B*16 = 4096; wave
                                            // reads 256 B fully contiguous
    const bool do_store = (u < 4);
    float* op = out + b * 4 + k;

    float h = 0.f, c = 0.f;

    float zv[8];
#pragma unroll
    for (int i = 0; i < 8; ++i) zv[i] = zp[(size_t)i * 4096];

    for (int t = 0; t < T_STEPS; t += 8) {
#pragma unroll
        for (int j = 0; j < 8; ++j) {
            int tt = t + j;

            float o = lstm_step(h, c, zv[j], wh0, wh1, wh2, wh3, s1c, m2, m3, k, b0g, b1g);

            if (do_store) op[(size_t)tt * (BATCH * 4)] = o;

            int tn = tt + 8;
            if (tn > T_STEPS - 1) tn = T_STEPS - 1;
            zv[j] = zp[(size_t)tn * 4096];
        }
    }

    if (do_store) {
        size_t hx_off = (size_t)T_STEPS * BATCH * 4;
        out[hx_off + b * 4 + k] = h;
        out[hx_off + BATCH * 4 + b * 4 + k] = c;
    }
}

extern "C" void kernel_launch(void* const* d_in, const int* in_sizes, int n_in,
                              void* d_out, int out_size, void* d_ws, size_t ws_size,
                              hipStream_t stream) {
    const float* x  = (const float*)d_in[0];
    const float* Wf = (const float*)d_in[1];
    const float* bf = (const float*)d_in[2];
    const float* tf = (const float*)d_in[3];
    const float* Wi = (const float*)d_in[4];
    const float* bi = (const float*)d_in[5];
    const float* ti = (const float*)d_in[6];
    const float* Wu = (const float*)d_in[7];
    const float* bu = (const float*)d_in[8];
    const float* tu = (const float*)d_in[9];
    const float* Wo = (const float*)d_in[10];
    const float* bo = (const float*)d_in[11];
    const float* to_ = (const float*)d_in[12];
    float* out = (float*)d_out;

    float* Zx = (float*)d_ws;                       // 33.6 MB
    float* Wc = Zx + ZX_FLOATS;                     // 8 KB
    float* bt = Wc + DIM * 16;                      // 64 B

    prep<<<1, 64, 0, stream>>>(Wf, bf, tf, Wi, bi, ti, Wu, bu, tu, Wo, bo, to_, Wc, bt);

    zx_gemm<<<(T_STEPS * BATCH) / 256, 256, 0, stream>>>(
        (const float4*)x, Wc, bt, (float4*)Zx);

    qlstm_rec<<<BATCH / 4, 64, 0, stream>>>(Zx, Wf, Wi, Wu, Wo, out);
}